// Round 2
// baseline (809.435 us; speedup 1.0000x reference)
//
#include <hip/hip_runtime.h>
#include <hip/hip_bf16.h>
#include <math.h>

// ef = [P_src | P_tgt] gathered per edge; z = attn * (ef @ [Wa1|We]) + bias
// (attn scalar commutes past We). All GEMMs bf16 MFMA 16x16x32, fp32 accum.
// R2: column-tiles strided across waves (ct = wv + 4n) so each wave's lanes
// hold matching zx/gate cols -> register epilogue, no Clds, 5 cheap barriers,
// LDS 37.6KB -> 4 blocks/CU.

typedef __bf16 bf16x8 __attribute__((ext_vector_type(8)));
typedef float f32x4 __attribute__((ext_vector_type(4)));

__device__ __forceinline__ unsigned short f2b(float f) {
    unsigned int u = __float_as_uint(f);
    unsigned int r = (u + 0x7fffu + ((u >> 16) & 1u)) >> 16;  // RNE
    return (unsigned short)r;
}

// ---- kernel 0: pack weights bf16, transposed to [n][k] for contiguous B-frags
__global__ __launch_bounds__(256) void pack_weights(
    const float* __restrict__ Ws, const float* __restrict__ Wt,
    const float* __restrict__ Wa1, const float* __restrict__ We,
    unsigned short* __restrict__ Wp1, unsigned short* __restrict__ Wp2)
{
    int id = blockIdx.x * 256 + threadIdx.x;
    if (id < 32768) {                      // Wp1[256][128]: [Ws|Wt] cols
        int n = id >> 7, k = id & 127;
        float v = (n < 128) ? Ws[k * 128 + n] : Wt[k * 128 + (n - 128)];
        Wp1[id] = f2b(v);
    }
    if (id < 98304) {                      // Wp2[384][256]: [Wa1|We] cols
        int n = id >> 8, k = id & 255;
        float v = (n < 128) ? Wa1[k * 128 + n] : We[k * 256 + (n - 128)];
        Wp2[id] = f2b(v);
    }
}

// ---- kernel 1: P[node][0:128]=emb@Ws+bs, P[node][128:256]=emb@Wt+bt (bf16)
// 64 nodes/block, wave wv owns col-tiles {wv, wv+4, wv+8, wv+12} x 4 M-tiles
__global__ __launch_bounds__(256) void node_proj(
    const float* __restrict__ emb, const unsigned short* __restrict__ Wp1,
    const float* __restrict__ bs, const float* __restrict__ bt,
    unsigned short* __restrict__ P, int NN)
{
    __shared__ unsigned short Alds[64][136];  // 64 nodes x 128 bf16, +8 pad
    int t = threadIdx.x;
    int base = blockIdx.x * 64;
    {
        int row = t >> 2, cb = (t & 3) * 32;
        int node = base + row; if (node >= NN) node = NN - 1;
        const float* sp = emb + (size_t)node * 128 + cb;
#pragma unroll
        for (int i = 0; i < 4; ++i) {
            float4 v0 = *(const float4*)(sp + i * 8);
            float4 v1 = *(const float4*)(sp + i * 8 + 4);
            union { uint4 u; unsigned short s[8]; } pk;
            pk.s[0] = f2b(v0.x); pk.s[1] = f2b(v0.y); pk.s[2] = f2b(v0.z); pk.s[3] = f2b(v0.w);
            pk.s[4] = f2b(v1.x); pk.s[5] = f2b(v1.y); pk.s[6] = f2b(v1.z); pk.s[7] = f2b(v1.w);
            *(uint4*)&Alds[row][cb + i * 8] = pk.u;
        }
    }
    __syncthreads();
    int wv = t >> 6, lane = t & 63, n15 = lane & 15, quad = lane >> 4;
    f32x4 z4 = {0.f, 0.f, 0.f, 0.f};
    f32x4 acc[16];
#pragma unroll
    for (int i = 0; i < 16; ++i) acc[i] = z4;
    for (int ks = 0; ks < 4; ++ks) {
        bf16x8 a[4];
#pragma unroll
        for (int m = 0; m < 4; ++m)
            a[m] = *(const bf16x8*)&Alds[m * 16 + n15][ks * 32 + quad * 8];
#pragma unroll
        for (int n = 0; n < 4; ++n) {
            const unsigned short* bp = Wp1 + (size_t)(((wv + 4 * n) * 16 + n15)) * 128 + ks * 32 + quad * 8;
            bf16x8 b = *(const bf16x8*)bp;
#pragma unroll
            for (int m = 0; m < 4; ++m)
                acc[n * 4 + m] = __builtin_amdgcn_mfma_f32_16x16x32_bf16(a[m], b, acc[n * 4 + m], 0, 0, 0);
        }
    }
#pragma unroll
    for (int n = 0; n < 4; ++n) {
        int col = (wv + 4 * n) * 16 + n15;
        float bias = (col < 128) ? bs[col] : bt[col - 128];
#pragma unroll
        for (int m = 0; m < 4; ++m)
#pragma unroll
            for (int r = 0; r < 4; ++r) {
                int node = base + m * 16 + quad * 4 + r;
                if (node < NN) P[(size_t)node * 256 + col] = f2b(acc[n * 4 + m][r] + bias);
            }
    }
}

// ---- kernel 2: per-edge fused attn-gate + edge MLP + GeGLU + LayerNorm
// wave wv owns ct = wv + 4n (n=0..5): n=0,1 attn cols; n=2,3 zx; n=4,5 gate
// (zx tile wv+8+4np pairs with gate tile wv+16+4np in the SAME lane)
__global__ __launch_bounds__(256, 4) void edge_kernel(
    const int* __restrict__ eidx, const unsigned short* __restrict__ P,
    const unsigned short* __restrict__ Wp2,
    const float* __restrict__ ba1, const float* __restrict__ Wa2,
    const float* __restrict__ ba2, const float* __restrict__ be,
    const float* __restrict__ gamma, const float* __restrict__ beta,
    float* __restrict__ out, int E)
{
    __shared__ unsigned short Alds[64][264];  // 64 edges x 256 bf16 (+8 pad)
    __shared__ float attnP[64][4];            // per-wave attn-dot partials
    __shared__ float lnP[64][4][2];           // per-wave LN partials (s1,s2)
    __shared__ float attnV[64];               // sigmoid(attn) per edge
    __shared__ float2 mrV[64];                // (mu, rsqrt) per edge
    int t = threadIdx.x;
    int base = blockIdx.x * 64;

    // stage ef tile: chunk c -> edge e=c>>5, part p=c&31; col offset = p*8
#pragma unroll
    for (int i = 0; i < 8; ++i) {
        int c = t + i * 256;
        int e = c >> 5, p = c & 31;
        int ge = base + e; if (ge >= E) ge = E - 1;
        int node = (p < 16) ? eidx[ge] : eidx[E + ge];
        *(uint4*)&Alds[e][p * 8] = *(const uint4*)(P + (size_t)node * 256 + p * 8);
    }
    __syncthreads();

    int wv = t >> 6, lane = t & 63, n15 = lane & 15, quad = lane >> 4;
    f32x4 z4 = {0.f, 0.f, 0.f, 0.f};
    f32x4 acc[24];
#pragma unroll
    for (int i = 0; i < 24; ++i) acc[i] = z4;

    for (int ks = 0; ks < 8; ++ks) {
        bf16x8 a[4];
#pragma unroll
        for (int m = 0; m < 4; ++m)
            a[m] = *(const bf16x8*)&Alds[m * 16 + n15][ks * 32 + quad * 8];
#pragma unroll
        for (int n = 0; n < 6; ++n) {
            const unsigned short* bp = Wp2 + (size_t)(((wv + 4 * n) * 16 + n15)) * 256 + ks * 32 + quad * 8;
            bf16x8 b = *(const bf16x8*)bp;
#pragma unroll
            for (int m = 0; m < 4; ++m)
                acc[n * 4 + m] = __builtin_amdgcn_mfma_f32_16x16x32_bf16(a[m], b, acc[n * 4 + m], 0, 0, 0);
        }
    }

    // ---- attention dot: relu(y[0:128]+ba1).Wa2, tiles n=0,1 ----
    float ap[16];
#pragma unroll
    for (int i = 0; i < 16; ++i) ap[i] = 0.f;
#pragma unroll
    for (int n = 0; n < 2; ++n) {
        int col = (wv + 4 * n) * 16 + n15;
        float a1 = ba1[col], w2 = Wa2[col];
#pragma unroll
        for (int m = 0; m < 4; ++m)
#pragma unroll
            for (int r = 0; r < 4; ++r) {
                float h = fmaxf(acc[n * 4 + m][r] + a1, 0.f);
                ap[m * 4 + r] = fmaf(h, w2, ap[m * 4 + r]);
            }
    }
#pragma unroll
    for (int i = 0; i < 16; ++i) {
        ap[i] += __shfl_xor(ap[i], 1); ap[i] += __shfl_xor(ap[i], 2);
        ap[i] += __shfl_xor(ap[i], 4); ap[i] += __shfl_xor(ap[i], 8);
    }
    if (n15 == 0) {
#pragma unroll
        for (int m = 0; m < 4; ++m)
#pragma unroll
            for (int r = 0; r < 4; ++r)
                attnP[m * 16 + quad * 4 + r][wv] = ap[m * 4 + r];
    }
    __syncthreads();
    if (t < 64) {
        float s = attnP[t][0] + attnP[t][1] + attnP[t][2] + attnP[t][3] + ba2[0];
        attnV[t] = 1.f / (1.f + expf(-s));
    }
    __syncthreads();

    // ---- GeGLU: z = attn*y + be; g = zx * gelu_exact(zg); LN partials ----
    float g[2][16], s1[16], s2[16];
#pragma unroll
    for (int i = 0; i < 16; ++i) { s1[i] = 0.f; s2[i] = 0.f; }
#pragma unroll
    for (int np = 0; np < 2; ++np) {
        int zi = (wv + 4 * np) * 16 + n15;   // output col in [0,128)
        float bx = be[zi], bg = be[128 + zi];
#pragma unroll
        for (int m = 0; m < 4; ++m)
#pragma unroll
            for (int r = 0; r < 4; ++r) {
                float at = attnV[m * 16 + quad * 4 + r];
                float zx = fmaf(at, acc[(2 + np) * 4 + m][r], bx);
                float zg = fmaf(at, acc[(4 + np) * 4 + m][r], bg);
                float gv = zx * (0.5f * zg * (1.f + erff(zg * 0.70710678118f)));
                g[np][m * 4 + r] = gv;
                s1[m * 4 + r] += gv;
                s2[m * 4 + r] = fmaf(gv, gv, s2[m * 4 + r]);
            }
    }
#pragma unroll
    for (int i = 0; i < 16; ++i) {
        s1[i] += __shfl_xor(s1[i], 1); s1[i] += __shfl_xor(s1[i], 2);
        s1[i] += __shfl_xor(s1[i], 4); s1[i] += __shfl_xor(s1[i], 8);
        s2[i] += __shfl_xor(s2[i], 1); s2[i] += __shfl_xor(s2[i], 2);
        s2[i] += __shfl_xor(s2[i], 4); s2[i] += __shfl_xor(s2[i], 8);
    }
    if (n15 == 0) {
#pragma unroll
        for (int m = 0; m < 4; ++m)
#pragma unroll
            for (int r = 0; r < 4; ++r) {
                lnP[m * 16 + quad * 4 + r][wv][0] = s1[m * 4 + r];
                lnP[m * 16 + quad * 4 + r][wv][1] = s2[m * 4 + r];
            }
    }
    __syncthreads();
    if (t < 64) {
        float S1 = lnP[t][0][0] + lnP[t][1][0] + lnP[t][2][0] + lnP[t][3][0];
        float S2 = lnP[t][0][1] + lnP[t][1][1] + lnP[t][2][1] + lnP[t][3][1];
        float mu = S1 * 0.0078125f;
        float var = S2 * 0.0078125f - mu * mu;
        float2 mr; mr.x = mu; mr.y = rsqrtf(var + 1e-5f);
        mrV[t] = mr;
    }
    __syncthreads();

    // ---- normalize + store ----
#pragma unroll
    for (int np = 0; np < 2; ++np) {
        int zi = (wv + 4 * np) * 16 + n15;
        float gm = gamma[zi], bt_ = beta[zi];
#pragma unroll
        for (int m = 0; m < 4; ++m)
#pragma unroll
            for (int r = 0; r < 4; ++r) {
                int row = m * 16 + quad * 4 + r;
                int edge = base + row;
                if (edge < E) {
                    float2 mr = mrV[row];
                    out[(size_t)edge * 128 + zi] = (g[np][m * 4 + r] - mr.x) * mr.y * gm + bt_;
                }
            }
    }
}

extern "C" void kernel_launch(void* const* d_in, const int* in_sizes, int n_in,
                              void* d_out, int out_size, void* d_ws, size_t ws_size,
                              hipStream_t stream) {
    const float* emb  = (const float*)d_in[0];
    const int*   eidx = (const int*)d_in[1];
    const float* Ws   = (const float*)d_in[2];
    const float* bs   = (const float*)d_in[3];
    const float* Wt   = (const float*)d_in[4];
    const float* bt   = (const float*)d_in[5];
    const float* Wa1  = (const float*)d_in[6];
    const float* ba1  = (const float*)d_in[7];
    const float* Wa2  = (const float*)d_in[8];
    const float* ba2  = (const float*)d_in[9];
    const float* We   = (const float*)d_in[10];
    const float* be   = (const float*)d_in[11];
    const float* gam  = (const float*)d_in[12];
    const float* bet  = (const float*)d_in[13];
    float* out = (float*)d_out;
    int NN = in_sizes[0] / 128;
    int E  = in_sizes[1] / 2;
    unsigned short* Wp1 = (unsigned short*)d_ws;       // 64 KB
    unsigned short* Wp2 = Wp1 + 32768;                 // 192 KB
    unsigned short* P   = Wp2 + 98304;                 // 25.6 MB
    hipLaunchKernelGGL(pack_weights, dim3(384), dim3(256), 0, stream,
                       Ws, Wt, Wa1, We, Wp1, Wp2);
    hipLaunchKernelGGL(node_proj, dim3((NN + 63) / 64), dim3(256), 0, stream,
                       emb, Wp1, bs, bt, P, NN);
    hipLaunchKernelGGL(edge_kernel, dim3((E + 63) / 64), dim3(256), 0, stream,
                       eidx, P, Wp2, ba1, Wa2, ba2, be, gam, bet, out, E);
}